// Round 1
// baseline (588.896 us; speedup 1.0000x reference)
//
#include <hip/hip_runtime.h>
#include <cstdint>
#include <cstddef>

// Problem constants (fixed by the harness shapes)
#define BSZ   4
#define MAXS  4096
#define NB    64      // MAXS/BLOCK
#define KH    8
#define GQ    4
#define DH    128     // head dim
#define DG    128     // gate hidden
#define KHGD  4096    // KH*GQ*DH  (q row stride)
#define GD    512     // GQ*DH     (per-head K extent)

// ---------------------------------------------------------------------------
// Kernel 1: Q projection (T x 512 @ 512 x 128 per head) + RMSNorm + RoPE,
// scatter into padded qr[b][h][s][128].
// Block: 256 threads. Tile: 64 rows (t) x 128 cols (o). K-chunks of 64.
// Thread tile: 4 rows x 8 cols, cols split {tc*4..+3, 64+tc*4..+3} so the
// rotate-half partner (o +/- 64) lives in the same thread.
// ---------------------------------------------------------------------------
__global__ __launch_bounds__(256, 2)
void qproj_kernel(const float* __restrict__ q,
                  const float* __restrict__ wq,
                  const float* __restrict__ qnw,
                  const float* __restrict__ cosq,
                  const float* __restrict__ sinq,
                  const int*   __restrict__ cu,
                  float* __restrict__ qr,
                  int T)
{
    __shared__ float At[64][68];    // [m][kk] +4 pad: 2-way max on scalar reads
    __shared__ float Bt[64][128];   // [kk][o]

    const int tid = threadIdx.x;
    const int h   = blockIdx.y;
    const int t0  = blockIdx.x * 64;
    const int tr  = tid >> 4;       // 0..15 row group -> rows tr*4..tr*4+3
    const int tc  = tid & 15;       // 0..15 col group -> cols tc*4 and 64+tc*4

    float acc[4][8];
#pragma unroll
    for (int j = 0; j < 4; ++j)
#pragma unroll
        for (int i = 0; i < 8; ++i) acc[j][i] = 0.f;

    const float* qb = q  + (size_t)t0 * KHGD + (size_t)h * GD;
    const float* wb = wq + (size_t)h * GD * DG;

    const float* Ar  = &At[tr * 4][0];
    const float* Bp0 = &Bt[0][tc * 4];
    const float* Bp1 = &Bt[0][64 + tc * 4];

    for (int kc = 0; kc < 8; ++kc) {
        const int kb = kc * 64;
        // stage A: 64 x 64 chunk of q (this head's K-slice)
#pragma unroll
        for (int i = 0; i < 4; ++i) {
            const int fid = tid + i * 256;
            const int m = fid >> 4, c4 = (fid & 15) * 4;
            const int mg = (t0 + m < T) ? m : 0;   // clamp (grid is exact anyway)
            const float4 v = *(const float4*)(qb + (size_t)mg * KHGD + kb + c4);
            *(float4*)&At[m][c4] = v;
        }
        // stage B: 64 x 128 chunk of wq[h]
#pragma unroll
        for (int i = 0; i < 8; ++i) {
            const int fid = tid + i * 256;
            const int kk = fid >> 5, o4 = (fid & 31) * 4;
            const float4 v = *(const float4*)(wb + (size_t)(kb + kk) * DG + o4);
            *(float4*)&Bt[kk][o4] = v;
        }
        __syncthreads();

#pragma unroll 8
        for (int kk = 0; kk < 64; ++kk) {
            const float a0 = Ar[kk];
            const float a1 = Ar[68 + kk];
            const float a2 = Ar[136 + kk];
            const float a3 = Ar[204 + kk];
            const float4 b0 = *(const float4*)(Bp0 + kk * 128);
            const float4 b1 = *(const float4*)(Bp1 + kk * 128);
#define QROW(j, aj)                                                         \
            acc[j][0] += aj * b0.x; acc[j][1] += aj * b0.y;                 \
            acc[j][2] += aj * b0.z; acc[j][3] += aj * b0.w;                 \
            acc[j][4] += aj * b1.x; acc[j][5] += aj * b1.y;                 \
            acc[j][6] += aj * b1.z; acc[j][7] += aj * b1.w;
            QROW(0, a0) QROW(1, a1) QROW(2, a2) QROW(3, a3)
#undef QROW
        }
        __syncthreads();
    }

    // ---- epilogue: RMSNorm (row of 128 via 16-lane shfl reduce) + RoPE ----
    const int cu1 = cu[1], cu2 = cu[2], cu3 = cu[3];
    const float4 w0 = *(const float4*)(qnw + tc * 4);
    const float4 w1 = *(const float4*)(qnw + 64 + tc * 4);

#pragma unroll
    for (int j = 0; j < 4; ++j) {
        const int t = t0 + tr * 4 + j;
        float ss = 0.f;
#pragma unroll
        for (int i = 0; i < 8; ++i) ss += acc[j][i] * acc[j][i];
        // reduce across the 16 lanes sharing this row (lane bits 0..3 = tc)
        ss += __shfl_xor(ss, 1);
        ss += __shfl_xor(ss, 2);
        ss += __shfl_xor(ss, 4);
        ss += __shfl_xor(ss, 8);
        const float r = 1.0f / sqrtf(ss * (1.0f / 128.0f) + 1e-6f);

        if (t < T) {
            int b = 0;
            if (t >= cu1) b = 1;
            if (t >= cu2) b = 2;
            if (t >= cu3) b = 3;
            const int cub = (b == 0) ? 0 : ((b == 1) ? cu1 : ((b == 2) ? cu2 : cu3));
            const int s = t - cub;

            float y[8];
            y[0] = acc[j][0] * r * w0.x; y[1] = acc[j][1] * r * w0.y;
            y[2] = acc[j][2] * r * w0.z; y[3] = acc[j][3] * r * w0.w;
            y[4] = acc[j][4] * r * w1.x; y[5] = acc[j][5] * r * w1.y;
            y[6] = acc[j][6] * r * w1.z; y[7] = acc[j][7] * r * w1.w;

            const float* cb = cosq + ((size_t)b * MAXS + s) * DG;
            const float* sb = sinq + ((size_t)b * MAXS + s) * DG;
            const float4 c0 = *(const float4*)(cb + tc * 4);
            const float4 c1 = *(const float4*)(cb + 64 + tc * 4);
            const float4 s0v = *(const float4*)(sb + tc * 4);
            const float4 s1v = *(const float4*)(sb + 64 + tc * 4);

            // o < 64:  out = y*cos - y[o+64]*sin ; o >= 64: out = y*cos + y[o-64]*sin
            float4 o0, o1;
            o0.x = y[0] * c0.x - y[4] * s0v.x;
            o0.y = y[1] * c0.y - y[5] * s0v.y;
            o0.z = y[2] * c0.z - y[6] * s0v.z;
            o0.w = y[3] * c0.w - y[7] * s0v.w;
            o1.x = y[4] * c1.x + y[0] * s1v.x;
            o1.y = y[5] * c1.y + y[1] * s1v.y;
            o1.z = y[6] * c1.z + y[2] * s1v.z;
            o1.w = y[7] * c1.w + y[3] * s1v.w;

            float* qrow = qr + (((size_t)b * KH + h) * MAXS + s) * DG;
            *(float4*)(qrow + tc * 4)      = o0;
            *(float4*)(qrow + 64 + tc * 4) = o1;
        }
    }
}

// ---------------------------------------------------------------------------
// Kernel 2: K path. One block per (b, blk): masked max+avg pool over <=64
// tokens, project kcat(256) @ wk[h](256x128), RMSNorm + RoPE, store
// TRANSPOSED krT[b][h][o][t] so the score kernel loads coalesced.
// ---------------------------------------------------------------------------
__global__ __launch_bounds__(256, 2)
void kproj_kernel(const float* __restrict__ k,
                  const float* __restrict__ wk,
                  const float* __restrict__ knw,
                  const float* __restrict__ cosk,
                  const float* __restrict__ sink,
                  const int*   __restrict__ cu,
                  float* __restrict__ krT)
{
    __shared__ float kcat[KH][2 * DH];   // 8 x 256

    const int tid = threadIdx.x;
    const int blk = blockIdx.x, b = blockIdx.y;
    const int lb = cu[b];
    const int L  = cu[b + 1] - lb;
    const int nv = min(64, L - blk * 64);
    if (nv <= 0) return;   // block-uniform: invalid block, outputs masked anyway

    // pooling: thread owns float4 at (h = tid>>5, d = (tid&31)*4)
    const float* kbase = k + (size_t)(lb + blk * 64) * (KH * DH) + tid * 4;
    float4 vmax = make_float4(-3.0e38f, -3.0e38f, -3.0e38f, -3.0e38f);
    float4 vsum = make_float4(0.f, 0.f, 0.f, 0.f);
#pragma unroll 4
    for (int j = 0; j < nv; ++j) {
        const float4 v = *(const float4*)(kbase + (size_t)j * (KH * DH));
        vmax.x = fmaxf(vmax.x, v.x); vmax.y = fmaxf(vmax.y, v.y);
        vmax.z = fmaxf(vmax.z, v.z); vmax.w = fmaxf(vmax.w, v.w);
        vsum.x += v.x; vsum.y += v.y; vsum.z += v.z; vsum.w += v.w;
    }
    {
        const float inv = 1.0f / (float)nv;
        const int hh = tid >> 5, dd = (tid & 31) * 4;
        *(float4*)&kcat[hh][dd] = vmax;
        const float4 va = make_float4(vsum.x * inv, vsum.y * inv, vsum.z * inv, vsum.w * inv);
        *(float4*)&kcat[hh][128 + dd] = va;
    }
    __syncthreads();

    // projection: thread -> (h = tid>>5, o = (tid&31)*4)
    const int h = tid >> 5, oc = tid & 31, o = oc * 4;
    float4 a4 = make_float4(0.f, 0.f, 0.f, 0.f);
    const float* wbb = wk + (size_t)h * (2 * DH) * DG + o;
#pragma unroll 8
    for (int kk = 0; kk < 2 * DH; ++kk) {
        const float a = kcat[h][kk];
        const float4 w = *(const float4*)(wbb + (size_t)kk * DG);
        a4.x += a * w.x; a4.y += a * w.y; a4.z += a * w.z; a4.w += a * w.w;
    }

    // RMSNorm across the 32 lanes sharing h (lane bits 0..4 = oc)
    float ss = a4.x * a4.x + a4.y * a4.y + a4.z * a4.z + a4.w * a4.w;
    ss += __shfl_xor(ss, 1);
    ss += __shfl_xor(ss, 2);
    ss += __shfl_xor(ss, 4);
    ss += __shfl_xor(ss, 8);
    ss += __shfl_xor(ss, 16);
    const float r = 1.0f / sqrtf(ss * (1.0f / 128.0f) + 1e-6f);

    const float4 wn = *(const float4*)(knw + o);
    const float y0 = a4.x * r * wn.x;
    const float y1 = a4.y * r * wn.y;
    const float y2 = a4.z * r * wn.z;
    const float y3 = a4.w * r * wn.w;

    // rotate-half partner: lane ^ 16  (o <-> o +/- 64)
    const float p0 = __shfl_xor(y0, 16);
    const float p1 = __shfl_xor(y1, 16);
    const float p2 = __shfl_xor(y2, 16);
    const float p3 = __shfl_xor(y3, 16);
    const float r0 = (oc < 16) ? -p0 : p0;
    const float r1 = (oc < 16) ? -p1 : p1;
    const float r2 = (oc < 16) ? -p2 : p2;
    const float r3 = (oc < 16) ? -p3 : p3;

    const float* cb = cosk + ((size_t)b * NB + blk) * DG + o;
    const float* sb = sink + ((size_t)b * NB + blk) * DG + o;
    const float4 c4 = *(const float4*)cb;
    const float4 s4 = *(const float4*)sb;

    float* ko = krT + (((size_t)b * KH + h) * DG + o) * NB + blk;
    ko[0 * NB] = y0 * c4.x + r0 * s4.x;
    ko[1 * NB] = y1 * c4.y + r1 * s4.y;
    ko[2 * NB] = y2 * c4.z + r2 * s4.z;
    ko[3 * NB] = y3 * c4.w + r3 * s4.w;
}

// ---------------------------------------------------------------------------
// Kernel 3: scores. One block per (b, h, 64-row chunk c). Rows in a chunk all
// share tmax = c (chunk-aligned), so compute t in [0, c] only; everything
// else is -1e20. qr staged transposed in LDS, kr[o][t] staged once.
// Thread tile: 4 s x 4 t (outer product), t-groups wave-uniform so low-c
// blocks skip whole waves.
// ---------------------------------------------------------------------------
__global__ __launch_bounds__(256, 2)
void score_kernel(const float* __restrict__ qr,
                  const float* __restrict__ krT,
                  const int*   __restrict__ cu,
                  float* __restrict__ out)
{
    __shared__ float qtT[64][68];   // [o-within-chunk][m]   (+4 pad)
    __shared__ float kt[128][64];   // [o][t]

    const int tid = threadIdx.x;
    const int c = blockIdx.x, h = blockIdx.y, b = blockIdx.z;
    const int L  = cu[b + 1] - cu[b];
    const int s0 = c * 64;
    float* ob = out + (((size_t)b * KH + h) * MAXS + s0) * NB;

    if (s0 >= L) {               // fully invalid rows: fill -1e20, done
        const float4 m4 = make_float4(-1e20f, -1e20f, -1e20f, -1e20f);
#pragma unroll
        for (int i = 0; i < 4; ++i)
            *(float4*)(ob + (size_t)(tid + i * 256) * 4) = m4;
        return;
    }
    const int nt = c + 1;        // valid t range [0, nt)

    // stage kr (whole 128 x 64 tile; cols >= ceil(L/64) are never consumed)
    const float* ktg = krT + ((size_t)b * KH + h) * DG * NB;
#pragma unroll
    for (int i = 0; i < 8; ++i) {
        const int fid = tid + i * 256;
        const int o = fid >> 4, tp = (fid & 15) * 4;
        *(float4*)&kt[o][tp] = *(const float4*)(ktg + (size_t)o * NB + tp);
    }

    const int ts = tid & 15;     // s group: rows ts*4..ts*4+3
    const int tq = tid >> 4;     // t group: cols tq*4..tq*4+3 (wave-uniform 16t)
    float acc[4][4];
#pragma unroll
    for (int j = 0; j < 4; ++j)
#pragma unroll
        for (int i = 0; i < 4; ++i) acc[j][i] = 0.f;

    const float* qg = qr + (((size_t)b * KH + h) * MAXS + s0) * DG;

    for (int ko = 0; ko < 128; ko += 64) {
        __syncthreads();         // protect qtT reuse; covers kt readiness too
        // stage q chunk transposed: qtT[oo][m] = qr[s0+m][ko+oo]
#pragma unroll
        for (int i = 0; i < 4; ++i) {
            const int fid = tid + i * 256;
            const int m = fid >> 4, c4 = (fid & 15) * 4;
            const float4 v = *(const float4*)(qg + (size_t)m * DG + ko + c4);
            qtT[c4 + 0][m] = v.x;
            qtT[c4 + 1][m] = v.y;
            qtT[c4 + 2][m] = v.z;
            qtT[c4 + 3][m] = v.w;
        }
        __syncthreads();

        if (tq * 4 < nt) {
#pragma unroll 8
            for (int oo = 0; oo < 64; ++oo) {
                const float4 av = *(const float4*)&qtT[oo][ts * 4];
                const float4 bv = *(const float4*)&kt[ko + oo][tq * 4];
                acc[0][0] += av.x * bv.x; acc[0][1] += av.x * bv.y;
                acc[0][2] += av.x * bv.z; acc[0][3] += av.x * bv.w;
                acc[1][0] += av.y * bv.x; acc[1][1] += av.y * bv.y;
                acc[1][2] += av.y * bv.z; acc[1][3] += av.y * bv.w;
                acc[2][0] += av.z * bv.x; acc[2][1] += av.z * bv.y;
                acc[2][2] += av.z * bv.z; acc[2][3] += av.z * bv.w;
                acc[3][0] += av.w * bv.x; acc[3][1] += av.w * bv.y;
                acc[3][2] += av.w * bv.z; acc[3][3] += av.w * bv.w;
            }
        }
    }

    const float scale = 0.08838834764831845f;   // 1/sqrt(128)
#pragma unroll
    for (int j = 0; j < 4; ++j) {
        const int s = s0 + ts * 4 + j;
        const bool sv = (s < L);
        float4 v;
        v.x = (sv && (tq * 4 + 0) < nt) ? acc[j][0] * scale : -1e20f;
        v.y = (sv && (tq * 4 + 1) < nt) ? acc[j][1] * scale : -1e20f;
        v.z = (sv && (tq * 4 + 2) < nt) ? acc[j][2] * scale : -1e20f;
        v.w = (sv && (tq * 4 + 3) < nt) ? acc[j][3] * scale : -1e20f;
        *(float4*)(ob + (size_t)(ts * 4 + j) * NB + tq * 4) = v;
    }
}

// ---------------------------------------------------------------------------
extern "C" void kernel_launch(void* const* d_in, const int* in_sizes, int n_in,
                              void* d_out, int out_size, void* d_ws, size_t ws_size,
                              hipStream_t stream)
{
    const float* q    = (const float*)d_in[0];
    const float* k    = (const float*)d_in[1];
    const float* wq   = (const float*)d_in[2];
    const float* wk   = (const float*)d_in[3];
    const float* qnw  = (const float*)d_in[4];
    const float* knw  = (const float*)d_in[5];
    const float* cosq = (const float*)d_in[6];
    const float* sinq = (const float*)d_in[7];
    const float* cosk = (const float*)d_in[8];
    const float* sink = (const float*)d_in[9];
    // d_in[10] attention_mask, d_in[12] unpad_indices, d_in[13] max_seqlen:
    // all derivable from cu_seqlens + block-causal structure -> never read.
    const int* cu = (const int*)d_in[11];

    const int T = in_sizes[0] / KHGD;   // 14848

    float* qr  = (float*)d_ws;                                  // 64 MB
    float* krT = qr + (size_t)BSZ * KH * MAXS * DG;             // +1 MB
    (void)ws_size; (void)n_in; (void)out_size;

    dim3 g1((T + 63) / 64, KH);
    qproj_kernel<<<g1, 256, 0, stream>>>(q, wq, qnw, cosq, sinq, cu, qr, T);
    kproj_kernel<<<dim3(NB, BSZ), 256, 0, stream>>>(k, wk, knw, cosk, sink, cu, krT);
    score_kernel<<<dim3(NB, KH, BSZ), 256, 0, stream>>>(qr, krT, cu, (float*)d_out);
}

// Round 2
// 513.725 us; speedup vs baseline: 1.1463x; 1.1463x over previous
//
#include <hip/hip_runtime.h>
#include <cstdint>
#include <cstddef>

#define BSZ   4
#define MAXS  4096
#define NB    64
#define KH    8
#define DH    128
#define DG    128
#define KHGD  4096   // KH*GQ*DH (q row stride)
#define GD    512    // per-head K extent

typedef __attribute__((ext_vector_type(8))) short  short8;
typedef __attribute__((ext_vector_type(4))) float  f32x4;

// fp32 -> bf16 (RNE) helpers. hi-as-f32-bits lets us form the residual exactly.
static __device__ __forceinline__ unsigned bf16hi_bits(float x) {
    unsigned u = __float_as_uint(x);
    return (u + 0x7FFFu + ((u >> 16) & 1u)) & 0xFFFF0000u;
}
static __device__ __forceinline__ unsigned short bf16_rne(float x) {
    unsigned u = __float_as_uint(x);
    return (unsigned short)((u + 0x7FFFu + ((u >> 16) & 1u)) >> 16);
}

// ---------------------------------------------------------------------------
// Prep: split wq into bf16 hi/lo packed in per-lane MFMA B-fragment order.
// Fragment (h,kt,kf,cf,split): 64 lanes x 8 bf16 (1KB). Lane l, elem j holds
// wq[h][kt*64+kf*32+(l>>4)*8+j][cf*16+(l&15)].
// ---------------------------------------------------------------------------
__global__ __launch_bounds__(256)
void prep_wq(const float* __restrict__ wq, unsigned short* __restrict__ Bp)
{
    const int wid  = blockIdx.x * 4 + (threadIdx.x >> 6);   // 0..1023
    const int lane = threadIdx.x & 63;
    const int h  = wid >> 7, kt = (wid >> 4) & 7, kf = (wid >> 3) & 1, cf = wid & 7;
    const int n  = cf * 16 + (lane & 15);
    const int k0 = kt * 64 + kf * 32 + (lane >> 4) * 8;

    short8 hi, lo;
#pragma unroll
    for (int j = 0; j < 8; ++j) {
        const float x = wq[(size_t)(h * GD + k0 + j) * DG + n];
        const unsigned hb = bf16hi_bits(x);
        hi[j] = (short)(hb >> 16);
        lo[j] = (short)bf16_rne(x - __uint_as_float(hb));
    }
    unsigned short* p = Bp + (size_t)wid * 1024 + lane * 8;
    *(short8*)p         = hi;
    *(short8*)(p + 512) = lo;
}

// ---------------------------------------------------------------------------
// Q path: MFMA bf16-split GEMM (64 rows x 128 cols per wave, K=512) + RMSNorm
// + RoPE; emits qr as bf16 hi/lo in unpadded [t][h][128] layout.
// 1-wave blocks, no LDS. A-frags direct from global q; B-frags from Bp (L2).
// ---------------------------------------------------------------------------
__global__ __launch_bounds__(64, 2)
void qproj_mfma(const float* __restrict__ q,
                const unsigned short* __restrict__ Bp,
                const float* __restrict__ qnw,
                const float* __restrict__ cosq,
                const float* __restrict__ sinq,
                const int*   __restrict__ cu,
                unsigned short* __restrict__ qh,
                unsigned short* __restrict__ ql,
                int T)
{
    const int lane = threadIdx.x;
    const int h    = blockIdx.x;           // fastest grid dim -> L2 reuse of cos/sin
    const int row0 = blockIdx.y * 64;
    const int lr = lane & 15, lq = lane >> 4;

    f32x4 acc[4][8];
#pragma unroll
    for (int rf = 0; rf < 4; ++rf)
#pragma unroll
        for (int cf = 0; cf < 8; ++cf) acc[rf][cf] = (f32x4){0.f, 0.f, 0.f, 0.f};

    const float* qb = q + (size_t)h * GD + lq * 8;
    const float* aptr[4];
#pragma unroll
    for (int rf = 0; rf < 4; ++rf) {
        int grow = row0 + rf * 16 + lr;
        if (grow > T - 1) grow = T - 1;
        aptr[rf] = qb + (size_t)grow * KHGD;
    }

    for (int kt = 0; kt < 8; ++kt) {
        const int kb = kt * 64;
#pragma unroll
        for (int kf = 0; kf < 2; ++kf) {
            f32x4 a0[4], a1[4];
#pragma unroll
            for (int rf = 0; rf < 4; ++rf) {
                const float* p = aptr[rf] + kb + kf * 32;
                a0[rf] = *(const f32x4*)p;
                a1[rf] = *(const f32x4*)(p + 4);
            }
            short8 ah[4], al[4];
#pragma unroll
            for (int rf = 0; rf < 4; ++rf) {
#pragma unroll
                for (int j = 0; j < 4; ++j) {
                    float x = a0[rf][j];
                    unsigned hb = bf16hi_bits(x);
                    ah[rf][j] = (short)(hb >> 16);
                    al[rf][j] = (short)bf16_rne(x - __uint_as_float(hb));
                    float y = a1[rf][j];
                    unsigned hb2 = bf16hi_bits(y);
                    ah[rf][j + 4] = (short)(hb2 >> 16);
                    al[rf][j + 4] = (short)bf16_rne(y - __uint_as_float(hb2));
                }
            }
            const unsigned short* bp =
                Bp + (size_t)(((h * 8 + kt) * 2 + kf) * 8) * 1024 + lane * 8;
#pragma unroll
            for (int cf = 0; cf < 8; ++cf) {
                const short8 bh = *(const short8*)(bp + cf * 1024);
                const short8 bl = *(const short8*)(bp + cf * 1024 + 512);
#pragma unroll
                for (int rf = 0; rf < 4; ++rf) {
                    acc[rf][cf] = __builtin_amdgcn_mfma_f32_16x16x32_bf16(ah[rf], bh, acc[rf][cf], 0, 0, 0);
                    acc[rf][cf] = __builtin_amdgcn_mfma_f32_16x16x32_bf16(ah[rf], bl, acc[rf][cf], 0, 0, 0);
                    acc[rf][cf] = __builtin_amdgcn_mfma_f32_16x16x32_bf16(al[rf], bh, acc[rf][cf], 0, 0, 0);
                }
            }
        }
    }

    // epilogue: RMSNorm (row of 128 across 16 lanes) + RoPE + bf16 split store
    const int cu1 = cu[1], cu2 = cu[2], cu3 = cu[3];
    float wn[8];
#pragma unroll
    for (int cf = 0; cf < 8; ++cf) wn[cf] = qnw[cf * 16 + lr];

#pragma unroll
    for (int rf = 0; rf < 4; ++rf) {
#pragma unroll
        for (int r = 0; r < 4; ++r) {
            float vv[8];
            float ss = 0.f;
#pragma unroll
            for (int cf = 0; cf < 8; ++cf) { vv[cf] = acc[rf][cf][r]; ss += vv[cf] * vv[cf]; }
            ss += __shfl_xor(ss, 1);
            ss += __shfl_xor(ss, 2);
            ss += __shfl_xor(ss, 4);
            ss += __shfl_xor(ss, 8);
            const float rn = 1.0f / sqrtf(ss * (1.0f / 128.0f) + 1e-6f);

            const int t = row0 + rf * 16 + lq * 4 + r;
            if (t < T) {
                int b = 0, cub = 0;
                if (t >= cu1) { b = 1; cub = cu1; }
                if (t >= cu2) { b = 2; cub = cu2; }
                if (t >= cu3) { b = 3; cub = cu3; }
                const int s = t - cub;

                float y[8];
#pragma unroll
                for (int cf = 0; cf < 8; ++cf) y[cf] = vv[cf] * rn * wn[cf];

                const float* cb = cosq + ((size_t)b * MAXS + s) * DG + lr;
                const float* sb = sinq + ((size_t)b * MAXS + s) * DG + lr;
                unsigned short* oh = qh + ((size_t)t * KH + h) * DG + lr;
                unsigned short* ol = ql + ((size_t)t * KH + h) * DG + lr;
#pragma unroll
                for (int cf = 0; cf < 8; ++cf) {
                    const float rot = (cf < 4) ? -y[cf + 4] : y[cf - 4];
                    const float o = y[cf] * cb[cf * 16] + rot * sb[cf * 16];
                    const unsigned hb = bf16hi_bits(o);
                    oh[cf * 16] = (unsigned short)(hb >> 16);
                    ol[cf * 16] = bf16_rne(o - __uint_as_float(hb));
                }
            }
        }
    }
}

// ---------------------------------------------------------------------------
// K path (small): pool + project + RMSNorm + RoPE, emit bf16 hi/lo kr[b][h][t][o].
// ---------------------------------------------------------------------------
__global__ __launch_bounds__(256, 2)
void kproj_kernel(const float* __restrict__ k,
                  const float* __restrict__ wk,
                  const float* __restrict__ knw,
                  const float* __restrict__ cosk,
                  const float* __restrict__ sink,
                  const int*   __restrict__ cu,
                  unsigned short* __restrict__ krh,
                  unsigned short* __restrict__ krl)
{
    __shared__ float kcat[KH][2 * DH];

    const int tid = threadIdx.x;
    const int blk = blockIdx.x, b = blockIdx.y;
    const int lb = cu[b];
    const int L  = cu[b + 1] - lb;
    const int nv = min(64, L - blk * 64);
    if (nv <= 0) return;

    const float* kbase = k + (size_t)(lb + blk * 64) * (KH * DH) + tid * 4;
    float4 vmax = make_float4(-3.0e38f, -3.0e38f, -3.0e38f, -3.0e38f);
    float4 vsum = make_float4(0.f, 0.f, 0.f, 0.f);
#pragma unroll 4
    for (int j = 0; j < nv; ++j) {
        const float4 v = *(const float4*)(kbase + (size_t)j * (KH * DH));
        vmax.x = fmaxf(vmax.x, v.x); vmax.y = fmaxf(vmax.y, v.y);
        vmax.z = fmaxf(vmax.z, v.z); vmax.w = fmaxf(vmax.w, v.w);
        vsum.x += v.x; vsum.y += v.y; vsum.z += v.z; vsum.w += v.w;
    }
    {
        const float inv = 1.0f / (float)nv;
        const int hh = tid >> 5, dd = (tid & 31) * 4;
        *(float4*)&kcat[hh][dd] = vmax;
        const float4 va = make_float4(vsum.x * inv, vsum.y * inv, vsum.z * inv, vsum.w * inv);
        *(float4*)&kcat[hh][128 + dd] = va;
    }
    __syncthreads();

    const int h = tid >> 5, oc = tid & 31, o = oc * 4;
    float4 a4 = make_float4(0.f, 0.f, 0.f, 0.f);
    const float* wbb = wk + (size_t)h * (2 * DH) * DG + o;
#pragma unroll 8
    for (int kk = 0; kk < 2 * DH; ++kk) {
        const float a = kcat[h][kk];
        const float4 w = *(const float4*)(wbb + (size_t)kk * DG);
        a4.x += a * w.x; a4.y += a * w.y; a4.z += a * w.z; a4.w += a * w.w;
    }

    float ss = a4.x * a4.x + a4.y * a4.y + a4.z * a4.z + a4.w * a4.w;
    ss += __shfl_xor(ss, 1);
    ss += __shfl_xor(ss, 2);
    ss += __shfl_xor(ss, 4);
    ss += __shfl_xor(ss, 8);
    ss += __shfl_xor(ss, 16);
    const float r = 1.0f / sqrtf(ss * (1.0f / 128.0f) + 1e-6f);

    const float4 wn = *(const float4*)(knw + o);
    const float y0 = a4.x * r * wn.x;
    const float y1 = a4.y * r * wn.y;
    const float y2 = a4.z * r * wn.z;
    const float y3 = a4.w * r * wn.w;

    const float p0 = __shfl_xor(y0, 16);
    const float p1 = __shfl_xor(y1, 16);
    const float p2 = __shfl_xor(y2, 16);
    const float p3 = __shfl_xor(y3, 16);
    const float r0 = (oc < 16) ? -p0 : p0;
    const float r1 = (oc < 16) ? -p1 : p1;
    const float r2 = (oc < 16) ? -p2 : p2;
    const float r3 = (oc < 16) ? -p3 : p3;

    const float* cb = cosk + ((size_t)b * NB + blk) * DG + o;
    const float* sb = sink + ((size_t)b * NB + blk) * DG + o;
    const float4 c4 = *(const float4*)cb;
    const float4 s4 = *(const float4*)sb;

    float v[4];
    v[0] = y0 * c4.x + r0 * s4.x;
    v[1] = y1 * c4.y + r1 * s4.y;
    v[2] = y2 * c4.z + r2 * s4.z;
    v[3] = y3 * c4.w + r3 * s4.w;

    ushort4 sh, sl;
    unsigned hb;
    hb = bf16hi_bits(v[0]); sh.x = (unsigned short)(hb >> 16); sl.x = bf16_rne(v[0] - __uint_as_float(hb));
    hb = bf16hi_bits(v[1]); sh.y = (unsigned short)(hb >> 16); sl.y = bf16_rne(v[1] - __uint_as_float(hb));
    hb = bf16hi_bits(v[2]); sh.z = (unsigned short)(hb >> 16); sl.z = bf16_rne(v[2] - __uint_as_float(hb));
    hb = bf16hi_bits(v[3]); sh.w = (unsigned short)(hb >> 16); sl.w = bf16_rne(v[3] - __uint_as_float(hb));

    const size_t ko = (((size_t)b * KH + h) * NB + blk) * DG + o;
    *(ushort4*)(krh + ko) = sh;
    *(ushort4*)(krl + ko) = sl;
}

// ---------------------------------------------------------------------------
// Scores: MFMA bf16-split, no LDS. Block = (c,h,b), 4 waves x 16 rows.
// Causal: only col-frags cf with cf*16 < nt computed.
// ---------------------------------------------------------------------------
__global__ __launch_bounds__(256, 2)
void score_mfma(const unsigned short* __restrict__ qh,
                const unsigned short* __restrict__ ql,
                const unsigned short* __restrict__ krh,
                const unsigned short* __restrict__ krl,
                const int* __restrict__ cu,
                float* __restrict__ out, int T)
{
    const int tid = threadIdx.x;
    const int lane = tid & 63, wid = tid >> 6;
    const int c = blockIdx.x, h = blockIdx.y, b = blockIdx.z;
    const int L = cu[b + 1] - cu[b];
    float* ob = out + (((size_t)b * KH + h) * MAXS + c * 64) * NB;

    if (c * 64 >= L) {
        const f32x4 m4 = (f32x4){-1e20f, -1e20f, -1e20f, -1e20f};
#pragma unroll
        for (int i = 0; i < 4; ++i) ((f32x4*)ob)[tid + i * 256] = m4;
        return;
    }
    const int nt  = c + 1;
    const int ncf = (nt + 15) >> 4;
    const int lr = lane & 15, lq = lane >> 4;

    int qrow = cu[b] + c * 64 + wid * 16 + lr;
    if (qrow > T - 1) qrow = T - 1;
    const unsigned short* qhp = qh + ((size_t)qrow * KH + h) * DG + lq * 8;
    const unsigned short* qlp = ql + ((size_t)qrow * KH + h) * DG + lq * 8;
    const unsigned short* kbh = krh + (((size_t)b * KH + h) * NB + lr) * DG + lq * 8;
    const unsigned short* kbl = krl + (((size_t)b * KH + h) * NB + lr) * DG + lq * 8;

    f32x4 acc[4];
#pragma unroll
    for (int cf = 0; cf < 4; ++cf) acc[cf] = (f32x4){0.f, 0.f, 0.f, 0.f};

#pragma unroll
    for (int kf = 0; kf < 4; ++kf) {
        const short8 ah = *(const short8*)(qhp + kf * 32);
        const short8 al = *(const short8*)(qlp + kf * 32);
#pragma unroll
        for (int cf = 0; cf < 4; ++cf) {
            if (cf < ncf) {
                const short8 bh = *(const short8*)(kbh + cf * 2048 + kf * 32);
                const short8 bl = *(const short8*)(kbl + cf * 2048 + kf * 32);
                acc[cf] = __builtin_amdgcn_mfma_f32_16x16x32_bf16(ah, bh, acc[cf], 0, 0, 0);
                acc[cf] = __builtin_amdgcn_mfma_f32_16x16x32_bf16(ah, bl, acc[cf], 0, 0, 0);
                acc[cf] = __builtin_amdgcn_mfma_f32_16x16x32_bf16(al, bh, acc[cf], 0, 0, 0);
            }
        }
    }

    const float scale = 0.08838834764831845f;
#pragma unroll
    for (int cf = 0; cf < 4; ++cf) {
        const int t = cf * 16 + lr;
#pragma unroll
        for (int r = 0; r < 4; ++r) {
            const int srow = c * 64 + wid * 16 + lq * 4 + r;
            float v = (cf < ncf) ? acc[cf][r] * scale : -1e20f;
            v = (srow < L && t < nt) ? v : -1e20f;
            ob[(size_t)(wid * 16 + lq * 4 + r) * NB + t] = v;
        }
    }
}

// ---------------------------------------------------------------------------
extern "C" void kernel_launch(void* const* d_in, const int* in_sizes, int n_in,
                              void* d_out, int out_size, void* d_ws, size_t ws_size,
                              hipStream_t stream)
{
    const float* q    = (const float*)d_in[0];
    const float* k    = (const float*)d_in[1];
    const float* wq   = (const float*)d_in[2];
    const float* wk   = (const float*)d_in[3];
    const float* qnw  = (const float*)d_in[4];
    const float* knw  = (const float*)d_in[5];
    const float* cosq = (const float*)d_in[6];
    const float* sinq = (const float*)d_in[7];
    const float* cosk = (const float*)d_in[8];
    const float* sink = (const float*)d_in[9];
    const int*   cu   = (const int*)d_in[11];

    const int T = in_sizes[0] / KHGD;   // 14848

    unsigned short* qh  = (unsigned short*)d_ws;
    unsigned short* ql  = qh  + (size_t)T * KH * DG;                 // T*1024
    unsigned short* krh = ql  + (size_t)T * KH * DG;
    unsigned short* krl = krh + (size_t)BSZ * KH * NB * DG;          // 256K
    unsigned short* Bp  = krl + (size_t)BSZ * KH * NB * DG;          // 1M ushorts
    (void)ws_size; (void)n_in; (void)out_size;

    prep_wq<<<256, 256, 0, stream>>>(wq, Bp);
    kproj_kernel<<<dim3(NB, BSZ), 256, 0, stream>>>(k, wk, knw, cosk, sink, cu, krh, krl);
    qproj_mfma<<<dim3(KH, (T + 63) / 64), 64, 0, stream>>>(q, Bp, qnw, cosq, sinq, cu, qh, ql, T);
    score_mfma<<<dim3(NB, KH, BSZ), 256, 0, stream>>>(qh, ql, krh, krl, cu, (float*)d_out, T);
}